// Round 11
// baseline (76.592 us; speedup 1.0000x reference)
//
#include <hip/hip_runtime.h>
#include <math.h>

#define EMB 128
#define WIN 200
#define NT 64
#define BB 128
#define WPAD 208

typedef short bf16x8 __attribute__((ext_vector_type(8)));
typedef float f32x4  __attribute__((ext_vector_type(4)));

__device__ __forceinline__ unsigned pk2bf16(float a, float b) {    // RNE pack
    unsigned ua = __float_as_uint(a), ub = __float_as_uint(b);
    ua = (ua + 0x7FFFu + ((ua >> 16) & 1u)) >> 16;
    ub = (ub + 0x7FFFu + ((ub >> 16) & 1u)) >> 16;
    return ua | (ub << 16);
}
__device__ __forceinline__ float bf_lo(unsigned u) { return __uint_as_float(u << 16); }
__device__ __forceinline__ float bf_hi(unsigned u) { return __uint_as_float(u & 0xFFFF0000u); }
__device__ __forceinline__ float rdlane(float v, int l) {
    return __uint_as_float(__builtin_amdgcn_readlane(__float_as_uint(v), l));
}

// ---------------------------------------------------------------------------
// proj via MFMA (R9-verified fragment code). blocks [0,128) -> hp (titems,
// row-major fp32); [128,528) -> hq (citems, +Wb, fp32 hqT[b][nc][wpad][4]);
// block 528 -> mask-storage detect (bool-1B vs int32; 6400 int32 = 25600 B is
// safe under both layouts). B is staged from Ww fp32 with in-block bf16 cvt
// (prep kernel deleted). 64 rows/block, 256 thr = 4 waves x 16 rows.
// A,B XOR-swizzled LDS (16B-slot ^= row&7). C map: col=lane&15,
// row=(lane>>4)*4+reg (m89-verified).
// ---------------------------------------------------------------------------
__global__ __launch_bounds__(256, 4) void proj_kernel(
    const float* __restrict__ tvecs, const float* __restrict__ cvecs,
    const int* __restrict__ titems, const int* __restrict__ citems,
    const float* __restrict__ Ww, const float* __restrict__ Wbias,
    const int* __restrict__ mi, int* __restrict__ flag,
    float* __restrict__ hp_out, float* __restrict__ hqT_out)
{
    __shared__ __align__(16) ushort s_A[64 * 128];    // 16 KB, swizzled
    __shared__ __align__(16) ushort s_B[128 * 128];   // 32 KB, swizzled
    __shared__ float s_bias[128];
    __shared__ int   sdet;

    const int tid = threadIdx.x;

    if (blockIdx.x == 528) {                          // mask-storage detect
        if (tid == 0) sdet = 0;
        __syncthreads();
        int bad = 0;
        for (int i = tid; i < 6400; i += 256)
            if ((unsigned)mi[i] > 1u) bad = 1;
        if (bad) sdet = 1;
        __syncthreads();
        if (tid == 0) flag[0] = sdet;
        return;
    }

    const bool is_hp = blockIdx.x < 128;
    const float* table = is_hp ? tvecs : cvecs;
    const int*   idx   = is_hp ? titems : citems;
    const int  rbase = (is_hp ? blockIdx.x : (blockIdx.x - 128)) * 64;
    const int  eoff  = is_hp ? 0 : EMB;

    if (tid < 128) s_bias[tid] = Wbias[tid];

    // stage A: 64 rows x 128 k, gather + cvt bf16, swizzled 8B writes
    for (int i = tid; i < 2048; i += 256) {
        int row = i >> 5, j = i & 31;                 // k0 = 4*j
        float4 v = *(const float4*)&table[(size_t)idx[rbase + row] * 128 + 4 * j];
        uint2 p; p.x = pk2bf16(v.x, v.y); p.y = pk2bf16(v.z, v.w);
        *(uint2*)((char*)s_A + row * 256 + (((j >> 1) ^ (row & 7)) << 4) + (j & 1) * 8) = p;
    }
    // stage B: 128 n x 128 k from Ww fp32 (+cvt), swizzled 8B writes
    for (int i = tid; i < 4096; i += 256) {
        int n = i >> 5, j = i & 31;                   // 4 k per iter
        float4 v = *(const float4*)&Ww[n * 256 + eoff + 4 * j];
        uint2 p; p.x = pk2bf16(v.x, v.y); p.y = pk2bf16(v.z, v.w);
        *(uint2*)((char*)s_B + n * 256 + (((j >> 1) ^ (n & 7)) << 4) + (j & 1) * 8) = p;
    }
    __syncthreads();

    const int wid = tid >> 6, l = tid & 63;
    const int rl = l & 15, kg = l >> 4;
    const int r0 = wid * 16;

    f32x4 acc[8];
#pragma unroll
    for (int i = 0; i < 8; ++i) acc[i] = (f32x4){0.f, 0.f, 0.f, 0.f};

    const int arow = r0 + rl;
#pragma unroll
    for (int s = 0; s < 4; ++s) {
        bf16x8 af = *(const bf16x8*)((const char*)s_A
                        + arow * 256 + ((((s << 2) + kg) ^ (arow & 7)) << 4));
#pragma unroll
        for (int nt = 0; nt < 8; ++nt) {
            int bn = nt * 16 + rl;
            bf16x8 bfr = *(const bf16x8*)((const char*)s_B
                            + bn * 256 + ((((s << 2) + kg) ^ (bn & 7)) << 4));
            acc[nt] = __builtin_amdgcn_mfma_f32_16x16x32_bf16(af, bfr, acc[nt], 0, 0, 0);
        }
    }

    // C-write: row = (l>>4)*4 + i, col = nt*16 + (l&15)
#pragma unroll
    for (int i = 0; i < 4; ++i) {
        int ri = rbase + r0 + kg * 4 + i;
        if (is_hp) {
            size_t base = (size_t)ri * 128;
#pragma unroll
            for (int nt = 0; nt < 8; ++nt)
                hp_out[base + nt * 16 + rl] = acc[nt][i];
        } else {
            int b2 = ri / 200;                        // magic-mul
            int wl = ri - b2 * 200;
#pragma unroll
            for (int nt = 0; nt < 8; ++nt) {
                int col = nt * 16 + rl;
                hqT_out[(((size_t)b2 * 32 + (col >> 2)) * WPAD + wl) * 4 + (col & 3)]
                    = acc[nt][i] + s_bias[col];
            }
        }
    }
}

// ---------------------------------------------------------------------------
// attn: grid 1024 = (b, 8-t eighth), 256 thr = 4 waves, wave owns 2 t.
// LDS ~37 KB -> 4 blocks/CU (vs 1 in R6): compacted hq staged as bf16 uint2
// slots [nc][swz(w')] (32 KB), hp bf16 (2 KB); PV direct from cvecs/L2 (fp32,
// exact). Softmax in regs (wave-local). m>128 fallback: R5-verified direct-
// from-global score path. XCD-chunked block swizzle (1024 % 8 == 0).
// ---------------------------------------------------------------------------
__global__ __launch_bounds__(256, 4) void attn_kernel(
    const float* __restrict__ cvecs, const int* __restrict__ citems,
    const void* __restrict__ mask_raw, const int* __restrict__ flagp,
    const float* __restrict__ hwg, const float* __restrict__ hp,
    const float* __restrict__ hqT, float* __restrict__ outp)
{
    __shared__ __align__(16) uint2  s_hq2[32 * 128];  // 32 KB bf16x4 slots
    __shared__ __align__(16) ushort s_hp[8 * 128];    // 2 KB bf16
    __shared__ float    s_hw[128];
    __shared__ int      s_ci[WIN], s_widx[WIN];
    __shared__ unsigned s_coff[WIN];
    __shared__ int      s_m;

    const int tid  = threadIdx.x;
    const int bid  = blockIdx.x;
    const int swz  = (bid & 7) * 128 + (bid >> 3);    // bijective
    const int b    = swz >> 3;
    const int tb   = (swz & 7) * 8;
    const int lane = tid & 63;
    const int wid  = tid >> 6;
    const int t0   = wid * 2;                         // local t base

    // ---- stage hp (8 t, fp32 -> bf16), hw, citems; wave0 compaction ----
    {
        int t = tid >> 5, e4 = tid & 31;
        float4 v = *(const float4*)&hp[((size_t)(b * 64 + tb + t)) * 128 + e4 * 4];
        uint2 p; p.x = pk2bf16(v.x, v.y); p.y = pk2bf16(v.z, v.w);
        *(uint2*)&s_hp[t * 128 + e4 * 4] = p;
    }
    if (tid < 128) s_hw[tid] = hwg[tid];
    if (tid < WIN) s_ci[tid] = citems[b * WIN + tid];
    if (wid == 0) {
        const int boolmode = flagp[0];
        const unsigned char* mb = (const unsigned char*)mask_raw;
        const int*           mi = (const int*)mask_raw;
        int base = 0;
#pragma unroll
        for (int r = 0; r < 4; ++r) {
            int w  = r * 64 + lane;
            int mv = 1;
            if (w < WIN) mv = boolmode ? (int)mb[b * WIN + w] : mi[b * WIN + w];
            unsigned long long act = __ballot(mv == 0);
            if (mv == 0)
                s_widx[base + __popcll(act & ((1ull << lane) - 1ull))] = w;
            base += __popcll(act);
        }
        if (lane == 0) s_m = base;
    }
    __syncthreads();

    const int m = s_m;
    const float invn = 1.f / sqrtf(800.f + (float)m);   // 1000 - (200 - m)
    size_t orow = ((size_t)(b * 64 + tb + t0)) * 128;
    if (m == 0) {
        *(float2*)&outp[orow + lane * 2]       = make_float2(0.f, 0.f);
        *(float2*)&outp[orow + 128 + lane * 2] = make_float2(0.f, 0.f);
        return;
    }
    const int mc = m - 1;
    if (tid < m) s_coff[tid] = (unsigned)s_ci[s_widx[tid]] * 512u;

    const float4* hq4g = (const float4*)hqT + (size_t)b * 32 * WPAD;
    const float4* hw4p = (const float4*)s_hw;
    const uint2*  hp2  = (const uint2*)s_hp;           // index t*32 + nc
    const char*   cvb  = (const char*)cvecs;

#define SCB(J, K, HA, HB, HC, HD)                                              \
    va[J][K] += hwv.x * fmaxf(HA + pa, 0.f) + hwv.y * fmaxf(HB + pb, 0.f)      \
              + hwv.z * fmaxf(HC + pc, 0.f) + hwv.w * fmaxf(HD + pd, 0.f);
#define SCF(J, K, HV)                                                          \
    va[J][K] += hwv.x * fmaxf(HV.x + pa, 0.f) + hwv.y * fmaxf(HV.y + pb, 0.f)  \
              + hwv.z * fmaxf(HV.z + pc, 0.f) + hwv.w * fmaxf(HV.w + pd, 0.f);

    if (m <= 128) {
        // ---- gather compacted hq (fp32 ws -> bf16 LDS, XOR-swz slots) ----
        for (int i = tid; i < 4096; i += 256) {
            int nc = i >> 7, w2 = i & 127;
            float4 v = hq4g[(size_t)nc * WPAD + s_widx[min(w2, mc)]];
            uint2 p; p.x = pk2bf16(v.x, v.y); p.y = pk2bf16(v.z, v.w);
            s_hq2[nc * 128 + (w2 ^ ((w2 >> 4) & 7))] = p;
        }
        __syncthreads();

        // ---- score ----
        const int sl0 = lane ^ ((lane >> 4) & 7);
        const int l64 = 64 + lane;
        const int sl1 = l64 ^ ((l64 >> 4) & 7);
        float va[2][2];
        va[0][0] = va[0][1] = va[1][0] = va[1][1] = 0.f;

#pragma unroll 4
        for (int nc = 0; nc < 32; ++nc) {
            uint2 h0 = s_hq2[nc * 128 + sl0];
            uint2 h1 = s_hq2[nc * 128 + sl1];
            float h0a = bf_lo(h0.x), h0b = bf_hi(h0.x), h0c = bf_lo(h0.y), h0d = bf_hi(h0.y);
            float h1a = bf_lo(h1.x), h1b = bf_hi(h1.x), h1c = bf_lo(h1.y), h1d = bf_hi(h1.y);
            float4 hwv = hw4p[nc];
#pragma unroll
            for (int jt = 0; jt < 2; ++jt) {
                uint2 pu = hp2[(t0 + jt) * 32 + nc];
                float pa = bf_lo(pu.x), pb = bf_hi(pu.x), pc = bf_lo(pu.y), pd = bf_hi(pu.y);
                SCB(jt, 0, h0a, h0b, h0c, h0d)
                SCB(jt, 1, h1a, h1b, h1c, h1d)
            }
        }

        // ---- softmax (2 tiles) ----
#pragma unroll
        for (int j = 0; j < 2; ++j) {
            float mx = -1e30f;
#pragma unroll
            for (int kt = 0; kt < 2; ++kt) {
                float v = (kt * 64 + lane < m) ? va[j][kt] : -1e30f;
                va[j][kt] = v;
                mx = fmaxf(mx, v);
            }
#pragma unroll
            for (int off = 32; off; off >>= 1) mx = fmaxf(mx, __shfl_xor(mx, off));
            float sum = 0.f;
#pragma unroll
            for (int kt = 0; kt < 2; ++kt) {
                float e = (va[j][kt] <= -1e29f) ? 0.f : __expf(va[j][kt] - mx);
                va[j][kt] = e;
                sum += e;
            }
#pragma unroll
            for (int off = 32; off; off >>= 1) sum += __shfl_xor(sum, off);
            float is = 1.f / sum;
            va[j][0] *= is; va[j][1] *= is;
        }

        // ---- PV direct from L2 (fp32 exact) ----
        float2 po0 = make_float2(0.f, 0.f), po1 = make_float2(0.f, 0.f);
#pragma unroll
        for (int kt = 0; kt < 2; ++kt) {
            if (kt * 64 < m) {
                const int wn = min(64, m - kt * 64);
#pragma unroll 4
                for (int w = 0; w < wn; ++w) {
                    float2 kv = *(const float2*)(cvb + s_coff[kt * 64 + w] + lane * 8);
                    float a0 = rdlane(va[0][kt], w);
                    float a1 = rdlane(va[1][kt], w);
                    po0.x += a0 * kv.x; po0.y += a0 * kv.y;
                    po1.x += a1 * kv.x; po1.y += a1 * kv.y;
                }
            }
        }
        *(float2*)&outp[orow + lane * 2]       = make_float2(po0.x * invn, po0.y * invn);
        *(float2*)&outp[orow + 128 + lane * 2] = make_float2(po1.x * invn, po1.y * invn);
    } else {
        // ---- m > 128 fallback (rare): direct-from-global fp32 score ----
        int wreg[4];
#pragma unroll
        for (int kt = 0; kt < 4; ++kt) wreg[kt] = s_widx[min(kt * 64 + lane, mc)];
        float va[2][4];
#pragma unroll
        for (int j = 0; j < 2; ++j)
#pragma unroll
            for (int k = 0; k < 4; ++k) va[j][k] = 0.f;

#pragma unroll 2
        for (int nc = 0; nc < 32; ++nc) {
            const float4* base = hq4g + (size_t)nc * WPAD;
            float4 hv0 = base[wreg[0]];
            float4 hv1 = base[wreg[1]];
            float4 hv2 = base[wreg[2]];
            float4 hv3 = base[wreg[3]];
            float4 hwv = hw4p[nc];
#pragma unroll
            for (int jt = 0; jt < 2; ++jt) {
                uint2 pu = hp2[(t0 + jt) * 32 + nc];
                float pa = bf_lo(pu.x), pb = bf_hi(pu.x), pc = bf_lo(pu.y), pd = bf_hi(pu.y);
                SCF(jt, 0, hv0) SCF(jt, 1, hv1) SCF(jt, 2, hv2) SCF(jt, 3, hv3)
            }
        }

#pragma unroll
        for (int j = 0; j < 2; ++j) {
            float mx = -1e30f;
#pragma unroll
            for (int kt = 0; kt < 4; ++kt) {
                float v = (kt * 64 + lane < m) ? va[j][kt] : -1e30f;
                va[j][kt] = v;
                mx = fmaxf(mx, v);
            }
#pragma unroll
            for (int off = 32; off; off >>= 1) mx = fmaxf(mx, __shfl_xor(mx, off));
            float sum = 0.f;
#pragma unroll
            for (int kt = 0; kt < 4; ++kt) {
                float e = (va[j][kt] <= -1e29f) ? 0.f : __expf(va[j][kt] - mx);
                va[j][kt] = e;
                sum += e;
            }
#pragma unroll
            for (int off = 32; off; off >>= 1) sum += __shfl_xor(sum, off);
            float is = 1.f / sum;
#pragma unroll
            for (int kt = 0; kt < 4; ++kt) va[j][kt] *= is;
        }

        float2 po0 = make_float2(0.f, 0.f), po1 = make_float2(0.f, 0.f);
#pragma unroll
        for (int kt = 0; kt < 4; ++kt) {
            if (kt * 64 < m) {
                const int wn = min(64, m - kt * 64);
#pragma unroll 4
                for (int w = 0; w < wn; ++w) {
                    float2 kv = *(const float2*)(cvb + s_coff[kt * 64 + w] + lane * 8);
                    float a0 = rdlane(va[0][kt], w);
                    float a1 = rdlane(va[1][kt], w);
                    po0.x += a0 * kv.x; po0.y += a0 * kv.y;
                    po1.x += a1 * kv.x; po1.y += a1 * kv.y;
                }
            }
        }
        *(float2*)&outp[orow + lane * 2]       = make_float2(po0.x * invn, po0.y * invn);
        *(float2*)&outp[orow + 128 + lane * 2] = make_float2(po1.x * invn, po1.y * invn);
    }
#undef SCB
#undef SCF
}

// ---------------------------------------------------------------------------
extern "C" void kernel_launch(void* const* d_in, const int* in_sizes, int n_in,
                              void* d_out, int out_size, void* d_ws, size_t ws_size,
                              hipStream_t stream) {
    const float* tvecs = (const float*)d_in[0];
    const float* cvecs = (const float*)d_in[1];
    const float* Ww    = (const float*)d_in[2];
    const float* Wb    = (const float*)d_in[3];
    const float* hw    = (const float*)d_in[4];
    // d_in[5] = h_b : unused (softmax shift-invariance)
    const int* titems  = (const int*)d_in[6];
    const int* citems  = (const int*)d_in[7];
    const void* mask   = d_in[8];
    float* out         = (float*)d_out;

    // ws: flag(64 i32) | hp (8192x128 f32) | hqT (128x32x208x4 f32)
    const size_t needed = (size_t)(64 + (size_t)BB * NT * 128
                                   + (size_t)BB * 32 * WPAD * 4) * 4;
    if (ws_size < needed) return;

    int*   flag   = (int*)d_ws;
    float* hp_ws  = (float*)d_ws + 64;
    float* hqT_ws = hp_ws + (size_t)BB * NT * 128;

    proj_kernel<<<529, 256, 0, stream>>>(tvecs, cvecs, titems, citems,
                                         Ww, Wb, (const int*)mask, flag,
                                         hp_ws, hqT_ws);
    attn_kernel<<<BB * 8, 256, 0, stream>>>(cvecs, citems, mask, flag,
                                            hw, hp_ws, hqT_ws, out);
}

// Round 12
// 51.989 us; speedup vs baseline: 1.4732x; 1.4732x over previous
//
#include <hip/hip_runtime.h>
#include <math.h>

#define EMB 128
#define WIN 200
#define NT 64
#define BB 128
#define WPAD 208

typedef short bf16x8 __attribute__((ext_vector_type(8)));
typedef float f32x4  __attribute__((ext_vector_type(4)));

__device__ __forceinline__ unsigned pk2bf16(float a, float b) {    // RNE pack
    unsigned ua = __float_as_uint(a), ub = __float_as_uint(b);
    ua = (ua + 0x7FFFu + ((ua >> 16) & 1u)) >> 16;
    ub = (ub + 0x7FFFu + ((ub >> 16) & 1u)) >> 16;
    return ua | (ub << 16);
}
__device__ __forceinline__ float rdlane(float v, int l) {
    return __uint_as_float(__builtin_amdgcn_readlane(__float_as_uint(v), l));
}

// ---------------------------------------------------------------------------
// proj via MFMA (R9-verified fragment code; R11-verified slimming).
// blocks [0,128) -> hp (titems, row-major fp32); [128,528) -> hq (citems,
// +Wb, fp32 hqT[b][nc][wpad][4]); block 528 -> mask-storage detect (bool-1B
// vs int32; 6400 int32 = 25600 B safe under both layouts). B staged from Ww
// fp32 with in-block bf16 cvt. 64 rows/block, 256 thr = 4 waves x 16 rows.
// A,B XOR-swizzled LDS (16B-slot ^= row&7). C map: col=lane&15,
// row=(lane>>4)*4+reg (m89-verified).
// ---------------------------------------------------------------------------
__global__ __launch_bounds__(256, 4) void proj_kernel(
    const float* __restrict__ tvecs, const float* __restrict__ cvecs,
    const int* __restrict__ titems, const int* __restrict__ citems,
    const float* __restrict__ Ww, const float* __restrict__ Wbias,
    const int* __restrict__ mi, int* __restrict__ flag,
    float* __restrict__ hp_out, float* __restrict__ hqT_out)
{
    __shared__ __align__(16) ushort s_A[64 * 128];    // 16 KB, swizzled
    __shared__ __align__(16) ushort s_B[128 * 128];   // 32 KB, swizzled
    __shared__ float s_bias[128];
    __shared__ int   sdet;

    const int tid = threadIdx.x;

    if (blockIdx.x == 528) {                          // mask-storage detect
        if (tid == 0) sdet = 0;
        __syncthreads();
        int bad = 0;
        for (int i = tid; i < 6400; i += 256)
            if ((unsigned)mi[i] > 1u) bad = 1;
        if (bad) sdet = 1;
        __syncthreads();
        if (tid == 0) flag[0] = sdet;
        return;
    }

    const bool is_hp = blockIdx.x < 128;
    const float* table = is_hp ? tvecs : cvecs;
    const int*   idx   = is_hp ? titems : citems;
    const int  rbase = (is_hp ? blockIdx.x : (blockIdx.x - 128)) * 64;
    const int  eoff  = is_hp ? 0 : EMB;

    if (tid < 128) s_bias[tid] = Wbias[tid];

    // stage A: 64 rows x 128 k, gather + cvt bf16, swizzled 8B writes
    for (int i = tid; i < 2048; i += 256) {
        int row = i >> 5, j = i & 31;                 // k0 = 4*j
        float4 v = *(const float4*)&table[(size_t)idx[rbase + row] * 128 + 4 * j];
        uint2 p; p.x = pk2bf16(v.x, v.y); p.y = pk2bf16(v.z, v.w);
        *(uint2*)((char*)s_A + row * 256 + (((j >> 1) ^ (row & 7)) << 4) + (j & 1) * 8) = p;
    }
    // stage B: 128 n x 128 k from Ww fp32 (+cvt), swizzled 8B writes
    for (int i = tid; i < 4096; i += 256) {
        int n = i >> 5, j = i & 31;                   // 4 k per iter
        float4 v = *(const float4*)&Ww[n * 256 + eoff + 4 * j];
        uint2 p; p.x = pk2bf16(v.x, v.y); p.y = pk2bf16(v.z, v.w);
        *(uint2*)((char*)s_B + n * 256 + (((j >> 1) ^ (n & 7)) << 4) + (j & 1) * 8) = p;
    }
    __syncthreads();

    const int wid = tid >> 6, l = tid & 63;
    const int rl = l & 15, kg = l >> 4;
    const int r0 = wid * 16;

    f32x4 acc[8];
#pragma unroll
    for (int i = 0; i < 8; ++i) acc[i] = (f32x4){0.f, 0.f, 0.f, 0.f};

    const int arow = r0 + rl;
#pragma unroll
    for (int s = 0; s < 4; ++s) {
        bf16x8 af = *(const bf16x8*)((const char*)s_A
                        + arow * 256 + ((((s << 2) + kg) ^ (arow & 7)) << 4));
#pragma unroll
        for (int nt = 0; nt < 8; ++nt) {
            int bn = nt * 16 + rl;
            bf16x8 bfr = *(const bf16x8*)((const char*)s_B
                            + bn * 256 + ((((s << 2) + kg) ^ (bn & 7)) << 4));
            acc[nt] = __builtin_amdgcn_mfma_f32_16x16x32_bf16(af, bfr, acc[nt], 0, 0, 0);
        }
    }

    // C-write: row = (l>>4)*4 + i, col = nt*16 + (l&15)
#pragma unroll
    for (int i = 0; i < 4; ++i) {
        int ri = rbase + r0 + kg * 4 + i;
        if (is_hp) {
            size_t base = (size_t)ri * 128;
#pragma unroll
            for (int nt = 0; nt < 8; ++nt)
                hp_out[base + nt * 16 + rl] = acc[nt][i];
        } else {
            int b2 = ri / 200;                        // magic-mul
            int wl = ri - b2 * 200;
#pragma unroll
            for (int nt = 0; nt < 8; ++nt) {
                int col = nt * 16 + rl;
                hqT_out[(((size_t)b2 * 32 + (col >> 2)) * WPAD + wl) * 4 + (col & 3)]
                    = acc[nt][i] + s_bias[col];
            }
        }
    }
}

// ---------------------------------------------------------------------------
// attn (R6/R9-verified, 26 us): one block per (b, 32-t half), 512 thr =
// 8 waves x 4 t. Compacted hq (64KB fp32) + compacted k rows (64KB fp32)
// staged ONCE per block in LDS; score/softmax/PV from LDS/regs. m>128
// fallback: direct-from-L2. R10/R11 lessons: do NOT split t finer (L2
// re-read amplification) and do NOT phase-serialize more work into this
// 1-block/CU kernel.
// ---------------------------------------------------------------------------
__global__ __launch_bounds__(512, 2) void attn_kernel(
    const float* __restrict__ cvecs, const int* __restrict__ citems,
    const void* __restrict__ mask_raw, const int* __restrict__ flagp,
    const float* __restrict__ hwg, const float* __restrict__ hp,
    const float* __restrict__ hqT, float* __restrict__ outp)
{
    __shared__ __align__(16) float4 s_hq4[32 * 128];  // [nc][w'] 64 KB
    __shared__ __align__(16) float4 s_k4[128 * 32];   // [w'][e4] 64 KB
    __shared__ __align__(16) float  s_hp[32 * 128];   // [lt][n] 16 KB
    __shared__ __align__(16) float  s_hw[128];
    __shared__ int s_ci[WIN];
    __shared__ int s_widx[WIN];
    __shared__ int s_m;

    const int tid  = threadIdx.x;
    const int b    = blockIdx.x >> 1;
    const int tb   = (blockIdx.x & 1) * 32;
    const int lane = tid & 63;
    const int wid  = tid >> 6;
    const int t0   = wid * 4;

    for (int i = tid; i < 1024; i += 512) {
        int t = i >> 5, e4 = i & 31;
        *(float4*)&s_hp[t * 128 + e4 * 4] =
            *(const float4*)&hp[((size_t)(b * 64 + tb + t)) * 128 + e4 * 4];
    }
    if (tid < 128) s_hw[tid] = hwg[tid];
    if (tid < WIN) s_ci[tid] = citems[b * WIN + tid];
    if (wid == 0) {
        const int boolmode = flagp[0];
        const unsigned char* mb = (const unsigned char*)mask_raw;
        const int*           mi = (const int*)mask_raw;
        int base = 0;
#pragma unroll
        for (int r = 0; r < 4; ++r) {
            int w  = r * 64 + lane;
            int mv = 1;
            if (w < WIN) mv = boolmode ? (int)mb[b * WIN + w] : mi[b * WIN + w];
            unsigned long long act = __ballot(mv == 0);
            if (mv == 0)
                s_widx[base + __popcll(act & ((1ull << lane) - 1ull))] = w;
            base += __popcll(act);
        }
        if (lane == 0) s_m = base;
    }
    __syncthreads();

    const int m = s_m;
    const float invn = 1.f / sqrtf(800.f + (float)m);   // 1000 - (200 - m)
    size_t orow = ((size_t)(b * 64 + tb + t0)) * 128;

    if (m == 0) {
#pragma unroll
        for (int j = 0; j < 4; ++j)
            *(float2*)&outp[orow + (size_t)j * 128 + lane * 2] = make_float2(0.f, 0.f);
        return;
    }

    const float4* hq4  = (const float4*)hqT + (size_t)b * 32 * WPAD;
    const float4* hp4a = (const float4*)&s_hp[t0 * 128];
    const float4* hw4p = (const float4*)s_hw;
    const float4* cv4  = (const float4*)cvecs;

#define SC(J, K, HV, P)                                                        \
    va[J][K] += hwv.x * fmaxf(HV.x + P.x, 0.f) + hwv.y * fmaxf(HV.y + P.y, 0.f)\
              + hwv.z * fmaxf(HV.z + P.z, 0.f) + hwv.w * fmaxf(HV.w + P.w, 0.f);

    if (m <= 128) {
        // ======================= staged fast path =======================
        {   // hq: [nc][w'] gather once
            const int w2 = tid & 127, nc0 = tid >> 7;
            if (w2 < m) {
                const int wi = s_widx[w2];
#pragma unroll
                for (int nc = nc0; nc < 32; nc += 4)
                    s_hq4[nc * 128 + w2] = hq4[(size_t)nc * WPAD + wi];
            }
            // k: [w'][e4] gather once (rows coalesced by 32 threads)
            const int e4 = tid & 31, w0 = tid >> 5;
            for (int w2k = w0; w2k < m; w2k += 16) {
                int ci = s_ci[s_widx[w2k]];
                s_k4[w2k * 32 + e4] = cv4[(size_t)ci * 32 + e4];
            }
        }
        __syncthreads();

        float va[4][2];
#pragma unroll
        for (int j = 0; j < 4; ++j) { va[j][0] = 0.f; va[j][1] = 0.f; }

#pragma unroll 2
        for (int nc = 0; nc < 32; ++nc) {
            float4 hv0 = s_hq4[nc * 128 + lane];
            float4 hv1 = s_hq4[nc * 128 + 64 + lane];
            float4 hwv = hw4p[nc];
            float4 p0  = hp4a[0 * 32 + nc];
            float4 p1  = hp4a[1 * 32 + nc];
            float4 p2  = hp4a[2 * 32 + nc];
            float4 p3  = hp4a[3 * 32 + nc];
            SC(0, 0, hv0, p0) SC(0, 1, hv1, p0)
            SC(1, 0, hv0, p1) SC(1, 1, hv1, p1)
            SC(2, 0, hv0, p2) SC(2, 1, hv1, p2)
            SC(3, 0, hv0, p3) SC(3, 1, hv1, p3)
        }

        // softmax over m compacted lanes (2 tiles)
#pragma unroll
        for (int j = 0; j < 4; ++j) {
            float mx = -1e30f;
#pragma unroll
            for (int kt = 0; kt < 2; ++kt) {
                float v = (kt * 64 + lane < m) ? va[j][kt] : -1e30f;
                va[j][kt] = v;
                mx = fmaxf(mx, v);
            }
#pragma unroll
            for (int off = 32; off; off >>= 1) mx = fmaxf(mx, __shfl_xor(mx, off));
            float sum = 0.f;
#pragma unroll
            for (int kt = 0; kt < 2; ++kt) {
                float e = (va[j][kt] <= -1e29f) ? 0.f : __expf(va[j][kt] - mx);
                va[j][kt] = e;
                sum += e;
            }
#pragma unroll
            for (int off = 32; off; off >>= 1) sum += __shfl_xor(sum, off);
            float is = 1.f / sum;
            va[j][0] *= is; va[j][1] *= is;
        }

        // PV from LDS k rows, att via readlane
        float2 po[4];
#pragma unroll
        for (int j = 0; j < 4; ++j) po[j] = make_float2(0.f, 0.f);
        const float2* s_k2 = (const float2*)s_k4;
#pragma unroll
        for (int kt = 0; kt < 2; ++kt) {
            if (kt * 64 < m) {
                const int wn = min(64, m - kt * 64);
                for (int w = 0; w < wn; ++w) {
                    float2 kv = s_k2[(kt * 64 + w) * 64 + lane];
                    float a0 = rdlane(va[0][kt], w);
                    float a1 = rdlane(va[1][kt], w);
                    float a2 = rdlane(va[2][kt], w);
                    float a3 = rdlane(va[3][kt], w);
                    po[0].x += a0 * kv.x; po[0].y += a0 * kv.y;
                    po[1].x += a1 * kv.x; po[1].y += a1 * kv.y;
                    po[2].x += a2 * kv.x; po[2].y += a2 * kv.y;
                    po[3].x += a3 * kv.x; po[3].y += a3 * kv.y;
                }
            }
        }
#pragma unroll
        for (int j = 0; j < 4; ++j)
            *(float2*)&outp[orow + (size_t)j * 128 + lane * 2] =
                make_float2(po[j].x * invn, po[j].y * invn);
    } else {
        // ================== direct fallback (m > 128, rare) ==================
        int wreg[4];
        const int mc = m - 1;
#pragma unroll
        for (int kt = 0; kt < 4; ++kt)
            wreg[kt] = s_widx[min(kt * 64 + lane, mc)];

        float va[4][4];
#pragma unroll
        for (int j = 0; j < 4; ++j)
#pragma unroll
            for (int k = 0; k < 4; ++k) va[j][k] = 0.f;

#pragma unroll 2
        for (int nc = 0; nc < 32; ++nc) {
            const float4* base = hq4 + (size_t)nc * WPAD;
            float4 hv0 = base[wreg[0]];
            float4 hv1 = base[wreg[1]];
            float4 hv2 = base[wreg[2]];
            float4 hv3 = base[wreg[3]];
            float4 hwv = hw4p[nc];
            float4 p0  = hp4a[0 * 32 + nc];
            float4 p1  = hp4a[1 * 32 + nc];
            float4 p2  = hp4a[2 * 32 + nc];
            float4 p3  = hp4a[3 * 32 + nc];
            SC(0, 0, hv0, p0) SC(0, 1, hv1, p0) SC(0, 2, hv2, p0) SC(0, 3, hv3, p0)
            SC(1, 0, hv0, p1) SC(1, 1, hv1, p1) SC(1, 2, hv2, p1) SC(1, 3, hv3, p1)
            SC(2, 0, hv0, p2) SC(2, 1, hv1, p2) SC(2, 2, hv2, p2) SC(2, 3, hv3, p2)
            SC(3, 0, hv0, p3) SC(3, 1, hv1, p3) SC(3, 2, hv2, p3) SC(3, 3, hv3, p3)
        }

#pragma unroll
        for (int j = 0; j < 4; ++j) {
            float mx = -1e30f;
#pragma unroll
            for (int kt = 0; kt < 4; ++kt) {
                float v = (kt * 64 + lane < m) ? va[j][kt] : -1e30f;
                va[j][kt] = v;
                mx = fmaxf(mx, v);
            }
#pragma unroll
            for (int off = 32; off; off >>= 1) mx = fmaxf(mx, __shfl_xor(mx, off));
            float sum = 0.f;
#pragma unroll
            for (int kt = 0; kt < 4; ++kt) {
                float e = (va[j][kt] <= -1e29f) ? 0.f : __expf(va[j][kt] - mx);
                va[j][kt] = e;
                sum += e;
            }
#pragma unroll
            for (int off = 32; off; off >>= 1) sum += __shfl_xor(sum, off);
            float is = 1.f / sum;
#pragma unroll
            for (int kt = 0; kt < 4; ++kt) va[j][kt] *= is;
        }

        float2 po[4];
#pragma unroll
        for (int j = 0; j < 4; ++j) po[j] = make_float2(0.f, 0.f);
        const char* cvb = (const char*)cvecs;
#pragma unroll
        for (int kt = 0; kt < 4; ++kt) {
            if (kt * 64 < m) {
                const int wn = min(64, m - kt * 64);
                for (int w = 0; w < wn; ++w) {
                    unsigned off = (unsigned)s_ci[s_widx[kt * 64 + w]] * 512u;
                    float2 kv = *(const float2*)(cvb + off + lane * 8);
                    float a0 = rdlane(va[0][kt], w);
                    float a1 = rdlane(va[1][kt], w);
                    float a2 = rdlane(va[2][kt], w);
                    float a3 = rdlane(va[3][kt], w);
                    po[0].x += a0 * kv.x; po[0].y += a0 * kv.y;
                    po[1].x += a1 * kv.x; po[1].y += a1 * kv.y;
                    po[2].x += a2 * kv.x; po[2].y += a2 * kv.y;
                    po[3].x += a3 * kv.x; po[3].y += a3 * kv.y;
                }
            }
        }
#pragma unroll
        for (int j = 0; j < 4; ++j)
            *(float2*)&outp[orow + (size_t)j * 128 + lane * 2] =
                make_float2(po[j].x * invn, po[j].y * invn);
    }
#undef SC
}

// ---------------------------------------------------------------------------
extern "C" void kernel_launch(void* const* d_in, const int* in_sizes, int n_in,
                              void* d_out, int out_size, void* d_ws, size_t ws_size,
                              hipStream_t stream) {
    const float* tvecs = (const float*)d_in[0];
    const float* cvecs = (const float*)d_in[1];
    const float* Ww    = (const float*)d_in[2];
    const float* Wb    = (const float*)d_in[3];
    const float* hw    = (const float*)d_in[4];
    // d_in[5] = h_b : unused (softmax shift-invariance)
    const int* titems  = (const int*)d_in[6];
    const int* citems  = (const int*)d_in[7];
    const void* mask   = d_in[8];
    float* out         = (float*)d_out;

    // ws: flag(64 i32) | hp (8192x128 f32) | hqT (128x32x208x4 f32)
    const size_t needed = (size_t)(64 + (size_t)BB * NT * 128
                                   + (size_t)BB * 32 * WPAD * 4) * 4;
    if (ws_size < needed) return;

    int*   flag   = (int*)d_ws;
    float* hp_ws  = (float*)d_ws + 64;
    float* hqT_ws = hp_ws + (size_t)BB * NT * 128;

    proj_kernel<<<529, 256, 0, stream>>>(tvecs, cvecs, titems, citems,
                                         Ww, Wb, (const int*)mask, flag,
                                         hp_ws, hqT_ws);
    attn_kernel<<<BB * 2, 512, 0, stream>>>(cvecs, citems, mask, flag,
                                            hw, hp_ws, hqT_ws, out);
}

// Round 13
// 50.421 us; speedup vs baseline: 1.5190x; 1.0311x over previous
//
#include <hip/hip_runtime.h>
#include <math.h>

#define EMB 128
#define WIN 200
#define NT 64
#define BB 128
#define WPAD 208

typedef short bf16x8 __attribute__((ext_vector_type(8)));
typedef float f32x4  __attribute__((ext_vector_type(4)));

__device__ __forceinline__ ushort bf16r(float x) {                 // RNE round
    unsigned u = __float_as_uint(x);
    return (ushort)((u + 0x7FFFu + ((u >> 16) & 1u)) >> 16);
}
__device__ __forceinline__ unsigned pk2bf16(float a, float b) {    // a=lo, b=hi
    unsigned ua = __float_as_uint(a), ub = __float_as_uint(b);
    ua = (ua + 0x7FFFu + ((ua >> 16) & 1u)) >> 16;
    ub = (ub + 0x7FFFu + ((ub >> 16) & 1u)) >> 16;
    return ua | (ub << 16);
}
__device__ __forceinline__ float bf_lo(unsigned u) { return __uint_as_float(u << 16); }
__device__ __forceinline__ float bf_hi(unsigned u) { return __uint_as_float(u & 0xFFFF0000u); }
__device__ __forceinline__ float rdlane(float v, int l) {
    return __uint_as_float(__builtin_amdgcn_readlane(__float_as_uint(v), l));
}

// ---------------------------------------------------------------------------
// proj via MFMA (R9-verified fragment code). 128 rows/block, 512 thr =
// 8 waves x 16 rows (halves the per-block W re-read vs 64-row blocks).
// blocks [0,64) -> hp (titems, bf16 [row][n]); [64,264) -> hq (citems, +Wb,
// bf16 packed hqT[b][nc][wpad] uint2 slots of 4 cols); block 264 -> mask-
// storage detect (bool-1B vs int32; 6400 int32 = 25600 B safe both layouts).
// A,B XOR-swizzled LDS (16B-slot ^= row&7). C map: col=lane&15,
// row=(lane>>4)*4+reg (m89-verified).
// ---------------------------------------------------------------------------
__global__ __launch_bounds__(512, 4) void proj_kernel(
    const float* __restrict__ tvecs, const float* __restrict__ cvecs,
    const int* __restrict__ titems, const int* __restrict__ citems,
    const float* __restrict__ Ww, const float* __restrict__ Wbias,
    const int* __restrict__ mi, int* __restrict__ flag,
    ushort* __restrict__ hp_out, ushort* __restrict__ hqT_out)
{
    __shared__ __align__(16) ushort s_A[128 * 128];   // 32 KB, swizzled
    __shared__ __align__(16) ushort s_B[128 * 128];   // 32 KB, swizzled
    __shared__ float s_bias[128];
    __shared__ int   sdet;

    const int tid = threadIdx.x;

    if (blockIdx.x == 264) {                          // mask-storage detect
        if (tid == 0) sdet = 0;
        __syncthreads();
        int bad = 0;
        for (int i = tid; i < 6400; i += 512)
            if ((unsigned)mi[i] > 1u) bad = 1;
        if (bad) sdet = 1;
        __syncthreads();
        if (tid == 0) flag[0] = sdet;
        return;
    }

    const bool is_hp = blockIdx.x < 64;
    const float* table = is_hp ? tvecs : cvecs;
    const int*   idx   = is_hp ? titems : citems;
    const int  rbase = (is_hp ? blockIdx.x : (blockIdx.x - 64)) * 128;
    const int  eoff  = is_hp ? 0 : EMB;

    if (tid < 128) s_bias[tid] = Wbias[tid];

    // stage A: 128 rows x 128 k, gather + cvt bf16, swizzled 8B writes
    for (int i = tid; i < 4096; i += 512) {
        int row = i >> 5, j = i & 31;                 // k0 = 4*j
        float4 v = *(const float4*)&table[(size_t)idx[rbase + row] * 128 + 4 * j];
        uint2 p; p.x = pk2bf16(v.x, v.y); p.y = pk2bf16(v.z, v.w);
        *(uint2*)((char*)s_A + row * 256 + (((j >> 1) ^ (row & 7)) << 4) + (j & 1) * 8) = p;
    }
    // stage B: 128 n x 128 k from Ww fp32 (+cvt), swizzled 8B writes
    for (int i = tid; i < 4096; i += 512) {
        int n = i >> 5, j = i & 31;
        float4 v = *(const float4*)&Ww[n * 256 + eoff + 4 * j];
        uint2 p; p.x = pk2bf16(v.x, v.y); p.y = pk2bf16(v.z, v.w);
        *(uint2*)((char*)s_B + n * 256 + (((j >> 1) ^ (n & 7)) << 4) + (j & 1) * 8) = p;
    }
    __syncthreads();

    const int wid = tid >> 6, l = tid & 63;
    const int rl = l & 15, kg = l >> 4;
    const int r0 = wid * 16;

    f32x4 acc[8];
#pragma unroll
    for (int i = 0; i < 8; ++i) acc[i] = (f32x4){0.f, 0.f, 0.f, 0.f};

    const int arow = r0 + rl;
#pragma unroll
    for (int s = 0; s < 4; ++s) {
        bf16x8 af = *(const bf16x8*)((const char*)s_A
                        + arow * 256 + ((((s << 2) + kg) ^ (arow & 7)) << 4));
#pragma unroll
        for (int nt = 0; nt < 8; ++nt) {
            int bn = nt * 16 + rl;
            bf16x8 bfr = *(const bf16x8*)((const char*)s_B
                            + bn * 256 + ((((s << 2) + kg) ^ (bn & 7)) << 4));
            acc[nt] = __builtin_amdgcn_mfma_f32_16x16x32_bf16(af, bfr, acc[nt], 0, 0, 0);
        }
    }

    // C-write (bf16): row = (l>>4)*4 + i, col = nt*16 + (l&15)
#pragma unroll
    for (int i = 0; i < 4; ++i) {
        int ri = rbase + r0 + kg * 4 + i;
        if (is_hp) {
            size_t base = (size_t)ri * 128;
#pragma unroll
            for (int nt = 0; nt < 8; ++nt)
                hp_out[base + nt * 16 + rl] = bf16r(acc[nt][i]);
        } else {
            int b2 = ri / 200;                        // magic-mul
            int wl = ri - b2 * 200;
#pragma unroll
            for (int nt = 0; nt < 8; ++nt) {
                int col = nt * 16 + rl;
                hqT_out[(((size_t)b2 * 32 + (col >> 2)) * WPAD + wl) * 4 + (col & 3)]
                    = bf16r(acc[nt][i] + s_bias[col]);
            }
        }
    }
}

// ---------------------------------------------------------------------------
// attn (R6-verified structure, bf16 LDS for 2 blocks/CU): one block per
// (b, 32-t half), 512 thr = 8 waves x 4 t. Compacted hq (32 KB bf16 slots) +
// compacted k rows (32 KB bf16) + hp (8 KB bf16) staged ONCE per block;
// score/softmax/PV from LDS/regs. LDS ~76 KB -> 2 blocks/CU so one block's
// gather overlaps the other's compute (R12 was 1 blk/CU, gather-latency-
// bound). PV k-bf16 error bound: max|k|*2^-9/norm ~= 2.5e-7 < threshold.
// m>128 fallback: direct-from-global (fp32 cvecs PV, bf16 hq score).
// ---------------------------------------------------------------------------
__global__ __launch_bounds__(512, 4) void attn_kernel(
    const float* __restrict__ cvecs, const int* __restrict__ citems,
    const void* __restrict__ mask_raw, const int* __restrict__ flagp,
    const float* __restrict__ hwg, const ushort* __restrict__ hp16,
    const ushort* __restrict__ hqT16, float* __restrict__ outp)
{
    __shared__ __align__(16) uint2  s_hq2[32 * 128];  // [nc][w'] 32 KB
    __shared__ __align__(16) ushort s_k[128 * 128];   // [w'][e]  32 KB
    __shared__ __align__(16) ushort s_hp[32 * 128];   // [t][n]    8 KB
    __shared__ float s_hw[128];
    __shared__ int s_ci[WIN];
    __shared__ int s_widx[WIN];
    __shared__ int s_m;

    const int tid  = threadIdx.x;
    const int b    = blockIdx.x >> 1;
    const int tb   = (blockIdx.x & 1) * 32;
    const int lane = tid & 63;
    const int wid  = tid >> 6;
    const int t0   = wid * 4;

    // ---- stage hp (bf16 direct copy), hw, citems; wave0 compaction ----
    for (int i = tid; i < 1024; i += 512)
        ((uint2*)s_hp)[i] = ((const uint2*)hp16)[((size_t)(b * 64 + tb)) * 32 + i];
    if (tid < 128) s_hw[tid] = hwg[tid];
    if (tid < WIN) s_ci[tid] = citems[b * WIN + tid];
    if (wid == 0) {
        const int boolmode = flagp[0];
        const unsigned char* mb = (const unsigned char*)mask_raw;
        const int*           mi = (const int*)mask_raw;
        int base = 0;
#pragma unroll
        for (int r = 0; r < 4; ++r) {
            int w  = r * 64 + lane;
            int mv = 1;
            if (w < WIN) mv = boolmode ? (int)mb[b * WIN + w] : mi[b * WIN + w];
            unsigned long long act = __ballot(mv == 0);
            if (mv == 0)
                s_widx[base + __popcll(act & ((1ull << lane) - 1ull))] = w;
            base += __popcll(act);
        }
        if (lane == 0) s_m = base;
    }
    __syncthreads();

    const int m = s_m;
    const float invn = 1.f / sqrtf(800.f + (float)m);   // 1000 - (200 - m)
    size_t orow = ((size_t)(b * 64 + tb + t0)) * 128;

    if (m == 0) {
#pragma unroll
        for (int j = 0; j < 4; ++j)
            *(float2*)&outp[orow + (size_t)j * 128 + lane * 2] = make_float2(0.f, 0.f);
        return;
    }

    const uint2* hq2g = (const uint2*)hqT16;          // slot = (b*32+nc)*WPAD + w
    const float4* hw4p = (const float4*)s_hw;
    const int mc = m - 1;

#define SCB(J, K, HA, HB, HC, HD)                                              \
    va[J][K] += hwv.x * fmaxf(HA + pa, 0.f) + hwv.y * fmaxf(HB + pb, 0.f)      \
              + hwv.z * fmaxf(HC + pc, 0.f) + hwv.w * fmaxf(HD + pd, 0.f);

    if (m <= 128) {
        // ======================= staged fast path =======================
        // hq: gather compacted bf16 slots
        for (int i = tid; i < 4096; i += 512) {
            int nc = i >> 7, w2 = i & 127;
            if (w2 < m)
                s_hq2[nc * 128 + w2] = hq2g[(size_t)(b * 32 + nc) * WPAD + s_widx[w2]];
        }
        // k: gather m rows, cvt to bf16 (16 thr/row, 8 e each)
        {
            const int er = tid & 15, wr = tid >> 4;
            for (int w2 = wr; w2 < m; w2 += 32) {
                const float4* src = (const float4*)&cvecs[(size_t)s_ci[s_widx[w2]] * 128 + er * 8];
                float4 a = src[0], c = src[1];
                uint4 p;
                p.x = pk2bf16(a.x, a.y); p.y = pk2bf16(a.z, a.w);
                p.z = pk2bf16(c.x, c.y); p.w = pk2bf16(c.z, c.w);
                *(uint4*)&s_k[w2 * 128 + er * 8] = p;
            }
        }
        __syncthreads();

        float va[4][2];
#pragma unroll
        for (int j = 0; j < 4; ++j) { va[j][0] = 0.f; va[j][1] = 0.f; }

#pragma unroll 2
        for (int nc = 0; nc < 32; ++nc) {
            uint2 h0 = s_hq2[nc * 128 + lane];
            uint2 h1 = s_hq2[nc * 128 + 64 + lane];
            float h0a = bf_lo(h0.x), h0b = bf_hi(h0.x), h0c = bf_lo(h0.y), h0d = bf_hi(h0.y);
            float h1a = bf_lo(h1.x), h1b = bf_hi(h1.x), h1c = bf_lo(h1.y), h1d = bf_hi(h1.y);
            float4 hwv = hw4p[nc];
#pragma unroll
            for (int jt = 0; jt < 4; ++jt) {
                uint2 pu = *(const uint2*)&s_hp[(t0 + jt) * 128 + nc * 4];
                float pa = bf_lo(pu.x), pb = bf_hi(pu.x), pc = bf_lo(pu.y), pd = bf_hi(pu.y);
                SCB(jt, 0, h0a, h0b, h0c, h0d)
                SCB(jt, 1, h1a, h1b, h1c, h1d)
            }
        }

        // softmax over m compacted lanes (2 tiles)
#pragma unroll
        for (int j = 0; j < 4; ++j) {
            float mx = -1e30f;
#pragma unroll
            for (int kt = 0; kt < 2; ++kt) {
                float v = (kt * 64 + lane < m) ? va[j][kt] : -1e30f;
                va[j][kt] = v;
                mx = fmaxf(mx, v);
            }
#pragma unroll
            for (int off = 32; off; off >>= 1) mx = fmaxf(mx, __shfl_xor(mx, off));
            float sum = 0.f;
#pragma unroll
            for (int kt = 0; kt < 2; ++kt) {
                float e = (va[j][kt] <= -1e29f) ? 0.f : __expf(va[j][kt] - mx);
                va[j][kt] = e;
                sum += e;
            }
#pragma unroll
            for (int off = 32; off; off >>= 1) sum += __shfl_xor(sum, off);
            float is = 1.f / sum;
            va[j][0] *= is; va[j][1] *= is;
        }

        // PV from LDS bf16 k rows, att via readlane
        float2 po[4];
#pragma unroll
        for (int j = 0; j < 4; ++j) po[j] = make_float2(0.f, 0.f);
#pragma unroll
        for (int kt = 0; kt < 2; ++kt) {
            if (kt * 64 < m) {
                const int wn = min(64, m - kt * 64);
                for (int w = 0; w < wn; ++w) {
                    unsigned ku = *(const unsigned*)&s_k[(kt * 64 + w) * 128 + lane * 2];
                    float kx = bf_lo(ku), ky = bf_hi(ku);
                    float a0 = rdlane(va[0][kt], w);
                    float a1 = rdlane(va[1][kt], w);
                    float a2 = rdlane(va[2][kt], w);
                    float a3 = rdlane(va[3][kt], w);
                    po[0].x += a0 * kx; po[0].y += a0 * ky;
                    po[1].x += a1 * kx; po[1].y += a1 * ky;
                    po[2].x += a2 * kx; po[2].y += a2 * ky;
                    po[3].x += a3 * kx; po[3].y += a3 * ky;
                }
            }
        }
#pragma unroll
        for (int j = 0; j < 4; ++j)
            *(float2*)&outp[orow + (size_t)j * 128 + lane * 2] =
                make_float2(po[j].x * invn, po[j].y * invn);
    } else {
        // ============ direct fallback (m > 128, rare): bf16 hq, fp32 PV ============
        int wreg[4];
#pragma unroll
        for (int kt = 0; kt < 4; ++kt)
            wreg[kt] = s_widx[min(kt * 64 + lane, mc)];

        float va[4][4];
#pragma unroll
        for (int j = 0; j < 4; ++j)
#pragma unroll
            for (int k = 0; k < 4; ++k) va[j][k] = 0.f;

#pragma unroll 2
        for (int nc = 0; nc < 32; ++nc) {
            const uint2* base = hq2g + (size_t)(b * 32 + nc) * WPAD;
            float h[4][4];
#pragma unroll
            for (int kt = 0; kt < 4; ++kt) {
                uint2 hu = base[wreg[kt]];
                h[kt][0] = bf_lo(hu.x); h[kt][1] = bf_hi(hu.x);
                h[kt][2] = bf_lo(hu.y); h[kt][3] = bf_hi(hu.y);
            }
            float4 hwv = hw4p[nc];
#pragma unroll
            for (int jt = 0; jt < 4; ++jt) {
                uint2 pu = *(const uint2*)&s_hp[(t0 + jt) * 128 + nc * 4];
                float pa = bf_lo(pu.x), pb = bf_hi(pu.x), pc = bf_lo(pu.y), pd = bf_hi(pu.y);
                SCB(jt, 0, h[0][0], h[0][1], h[0][2], h[0][3])
                SCB(jt, 1, h[1][0], h[1][1], h[1][2], h[1][3])
                SCB(jt, 2, h[2][0], h[2][1], h[2][2], h[2][3])
                SCB(jt, 3, h[3][0], h[3][1], h[3][2], h[3][3])
            }
        }

#pragma unroll
        for (int j = 0; j < 4; ++j) {
            float mx = -1e30f;
#pragma unroll
            for (int kt = 0; kt < 4; ++kt) {
                float v = (kt * 64 + lane < m) ? va[j][kt] : -1e30f;
                va[j][kt] = v;
                mx = fmaxf(mx, v);
            }
#pragma unroll
            for (int off = 32; off; off >>= 1) mx = fmaxf(mx, __shfl_xor(mx, off));
            float sum = 0.f;
#pragma unroll
            for (int kt = 0; kt < 4; ++kt) {
                float e = (va[j][kt] <= -1e29f) ? 0.f : __expf(va[j][kt] - mx);
                va[j][kt] = e;
                sum += e;
            }
#pragma unroll
            for (int off = 32; off; off >>= 1) sum += __shfl_xor(sum, off);
            float is = 1.f / sum;
#pragma unroll
            for (int kt = 0; kt < 4; ++kt) va[j][kt] *= is;
        }

        float2 po[4];
#pragma unroll
        for (int j = 0; j < 4; ++j) po[j] = make_float2(0.f, 0.f);
        const char* cvb = (const char*)cvecs;
#pragma unroll
        for (int kt = 0; kt < 4; ++kt) {
            if (kt * 64 < m) {
                const int wn = min(64, m - kt * 64);
                for (int w = 0; w < wn; ++w) {
                    unsigned off = (unsigned)s_ci[s_widx[kt * 64 + w]] * 512u;
                    float2 kv = *(const float2*)(cvb + off + lane * 8);
                    float a0 = rdlane(va[0][kt], w);
                    float a1 = rdlane(va[1][kt], w);
                    float a2 = rdlane(va[2][kt], w);
                    float a3 = rdlane(va[3][kt], w);
                    po[0].x += a0 * kv.x; po[0].y += a0 * kv.y;
                    po[1].x += a1 * kv.x; po[1].y += a1 * kv.y;
                    po[2].x += a2 * kv.x; po[2].y += a2 * kv.y;
                    po[3].x += a3 * kv.x; po[3].y += a3 * kv.y;
                }
            }
        }
#pragma unroll
        for (int j = 0; j < 4; ++j)
            *(float2*)&outp[orow + (size_t)j * 128 + lane * 2] =
                make_float2(po[j].x * invn, po[j].y * invn);
    }
#undef SCB
}

// ---------------------------------------------------------------------------
extern "C" void kernel_launch(void* const* d_in, const int* in_sizes, int n_in,
                              void* d_out, int out_size, void* d_ws, size_t ws_size,
                              hipStream_t stream) {
    const float* tvecs = (const float*)d_in[0];
    const float* cvecs = (const float*)d_in[1];
    const float* Ww    = (const float*)d_in[2];
    const float* Wb    = (const float*)d_in[3];
    const float* hw    = (const float*)d_in[4];
    // d_in[5] = h_b : unused (softmax shift-invariance)
    const int* titems  = (const int*)d_in[6];
    const int* citems  = (const int*)d_in[7];
    const void* mask   = d_in[8];
    float* out         = (float*)d_out;

    // ws: flag 256 B | hp16 (8192x128 bf16 = 2 MB) | hqT16 (128x32x208 slots x 8 B)
    const size_t hp_elems  = (size_t)BB * NT * 128;             // ushorts
    const size_t hq_elems  = (size_t)BB * 32 * WPAD * 4;        // ushorts
    const size_t needed = 256 + hp_elems * 2 + hq_elems * 2;
    if (ws_size < needed) return;

    int*    flag   = (int*)d_ws;
    ushort* hp16   = (ushort*)((char*)d_ws + 256);
    ushort* hqT16  = hp16 + hp_elems;

    proj_kernel<<<265, 512, 0, stream>>>(tvecs, cvecs, titems, citems,
                                         Ww, Wb, (const int*)mask, flag,
                                         hp16, hqT16);
    attn_kernel<<<BB * 2, 512, 0, stream>>>(cvecs, citems, mask, flag,
                                            hw, hp16, hqT16, out);
}

// Round 14
// 45.720 us; speedup vs baseline: 1.6752x; 1.1028x over previous
//
#include <hip/hip_runtime.h>
#include <math.h>

#define EMB 128
#define WIN 200
#define NT 64
#define BB 128
#define WPAD 208

typedef short bf16x8 __attribute__((ext_vector_type(8)));
typedef float f32x4  __attribute__((ext_vector_type(4)));

__device__ __forceinline__ ushort bf16r(float x) {                 // RNE round
    unsigned u = __float_as_uint(x);
    return (ushort)((u + 0x7FFFu + ((u >> 16) & 1u)) >> 16);
}
__device__ __forceinline__ unsigned pk2bf16(float a, float b) {    // a=lo, b=hi
    unsigned ua = __float_as_uint(a), ub = __float_as_uint(b);
    ua = (ua + 0x7FFFu + ((ua >> 16) & 1u)) >> 16;
    ub = (ub + 0x7FFFu + ((ub >> 16) & 1u)) >> 16;
    return ua | (ub << 16);
}
__device__ __forceinline__ float bf_lo(unsigned u) { return __uint_as_float(u << 16); }
__device__ __forceinline__ float bf_hi(unsigned u) { return __uint_as_float(u & 0xFFFF0000u); }
__device__ __forceinline__ float rdlane(float v, int l) {
    return __uint_as_float(__builtin_amdgcn_readlane(__float_as_uint(v), l));
}

// ---------------------------------------------------------------------------
// proj via MFMA (R13-verified). 128 rows/block, 512 thr = 8 waves x 16 rows.
// blocks [0,64) -> hp (titems, bf16 [row][n]); [64,264) -> hq (citems, +Wb,
// bf16 packed hqT[b][nc][wpad] uint2 slots); block 264 -> mask detect.
// A,B XOR-swizzled LDS (16B-slot ^= row&7). C map: col=lane&15,
// row=(lane>>4)*4+reg (m89-verified).
// ---------------------------------------------------------------------------
__global__ __launch_bounds__(512, 4) void proj_kernel(
    const float* __restrict__ tvecs, const float* __restrict__ cvecs,
    const int* __restrict__ titems, const int* __restrict__ citems,
    const float* __restrict__ Ww, const float* __restrict__ Wbias,
    const int* __restrict__ mi, int* __restrict__ flag,
    ushort* __restrict__ hp_out, ushort* __restrict__ hqT_out)
{
    __shared__ __align__(16) ushort s_A[128 * 128];   // 32 KB, swizzled
    __shared__ __align__(16) ushort s_B[128 * 128];   // 32 KB, swizzled
    __shared__ float s_bias[128];
    __shared__ int   sdet;

    const int tid = threadIdx.x;

    if (blockIdx.x == 264) {                          // mask-storage detect
        if (tid == 0) sdet = 0;
        __syncthreads();
        int bad = 0;
        for (int i = tid; i < 6400; i += 512)
            if ((unsigned)mi[i] > 1u) bad = 1;
        if (bad) sdet = 1;
        __syncthreads();
        if (tid == 0) flag[0] = sdet;
        return;
    }

    const bool is_hp = blockIdx.x < 64;
    const float* table = is_hp ? tvecs : cvecs;
    const int*   idx   = is_hp ? titems : citems;
    const int  rbase = (is_hp ? blockIdx.x : (blockIdx.x - 64)) * 128;
    const int  eoff  = is_hp ? 0 : EMB;

    if (tid < 128) s_bias[tid] = Wbias[tid];

    for (int i = tid; i < 4096; i += 512) {           // stage A (gather+cvt)
        int row = i >> 5, j = i & 31;
        float4 v = *(const float4*)&table[(size_t)idx[rbase + row] * 128 + 4 * j];
        uint2 p; p.x = pk2bf16(v.x, v.y); p.y = pk2bf16(v.z, v.w);
        *(uint2*)((char*)s_A + row * 256 + (((j >> 1) ^ (row & 7)) << 4) + (j & 1) * 8) = p;
    }
    for (int i = tid; i < 4096; i += 512) {           // stage B (Ww fp32 + cvt)
        int n = i >> 5, j = i & 31;
        float4 v = *(const float4*)&Ww[n * 256 + eoff + 4 * j];
        uint2 p; p.x = pk2bf16(v.x, v.y); p.y = pk2bf16(v.z, v.w);
        *(uint2*)((char*)s_B + n * 256 + (((j >> 1) ^ (n & 7)) << 4) + (j & 1) * 8) = p;
    }
    __syncthreads();

    const int wid = tid >> 6, l = tid & 63;
    const int rl = l & 15, kg = l >> 4;
    const int r0 = wid * 16;

    f32x4 acc[8];
#pragma unroll
    for (int i = 0; i < 8; ++i) acc[i] = (f32x4){0.f, 0.f, 0.f, 0.f};

    const int arow = r0 + rl;
#pragma unroll
    for (int s = 0; s < 4; ++s) {
        bf16x8 af = *(const bf16x8*)((const char*)s_A
                        + arow * 256 + ((((s << 2) + kg) ^ (arow & 7)) << 4));
#pragma unroll
        for (int nt = 0; nt < 8; ++nt) {
            int bn = nt * 16 + rl;
            bf16x8 bfr = *(const bf16x8*)((const char*)s_B
                            + bn * 256 + ((((s << 2) + kg) ^ (bn & 7)) << 4));
            acc[nt] = __builtin_amdgcn_mfma_f32_16x16x32_bf16(af, bfr, acc[nt], 0, 0, 0);
        }
    }

#pragma unroll
    for (int i = 0; i < 4; ++i) {
        int ri = rbase + r0 + kg * 4 + i;
        if (is_hp) {
            size_t base = (size_t)ri * 128;
#pragma unroll
            for (int nt = 0; nt < 8; ++nt)
                hp_out[base + nt * 16 + rl] = bf16r(acc[nt][i]);
        } else {
            int b2 = ri / 200;                        // magic-mul
            int wl = ri - b2 * 200;
#pragma unroll
            for (int nt = 0; nt < 8; ++nt) {
                int col = nt * 16 + rl;
                hqT_out[(((size_t)b2 * 32 + (col >> 2)) * WPAD + wl) * 4 + (col & 3)]
                    = bf16r(acc[nt][i] + s_bias[col]);
            }
        }
    }
}

// ---------------------------------------------------------------------------
// attn: one block per (b, 32-t half) — R6/R12-verified staging granularity —
// but 1024 threads (16 waves/CU, 50% occupancy; R13 was 8 waves + no 2nd
// block possible at grid 256 -> latency-bound). Wave owns 2 t. fp32 LDS:
// hq cvt'd bf16->fp32 ONCE at stage; k staged fp32 (exact PV). Score/softmax
// /PV are R12's verified fp32 loops. XCD-pair swizzle: a b's two halves on
// one XCD for hq/k L2 reuse. m>128 fallback: direct-from-global.
// ---------------------------------------------------------------------------
__global__ __launch_bounds__(1024, 1) void attn_kernel(
    const float* __restrict__ cvecs, const int* __restrict__ citems,
    const void* __restrict__ mask_raw, const int* __restrict__ flagp,
    const float* __restrict__ hwg, const ushort* __restrict__ hp16,
    const ushort* __restrict__ hqT16, float* __restrict__ outp)
{
    __shared__ __align__(16) float4 s_hq4[32 * 128];  // [nc][w'] 64 KB fp32
    __shared__ __align__(16) float4 s_k4[128 * 32];   // [w'][e4] 64 KB fp32
    __shared__ __align__(16) float  s_hp[32 * 128];   // [t][n]   16 KB fp32
    __shared__ float s_hw[128];
    __shared__ int s_ci[WIN];
    __shared__ int s_widx[WIN];
    __shared__ int s_m;

    const int tid  = threadIdx.x;
    const int bid  = blockIdx.x;
    const int swz  = (bid & 7) * 32 + (bid >> 3);     // bijective; pairs share XCD
    const int b    = swz >> 1;
    const int tb   = (swz & 1) * 32;
    const int lane = tid & 63;
    const int wid  = tid >> 6;                        // 0..15
    const int t0   = wid * 2;

    // ---- stage hp (bf16 -> fp32), hw, citems; wave0 compaction ----
    {
        int t = tid >> 5, e4 = tid & 31;              // 1024 = 32 t x 32 f4
        uint2 p = *(const uint2*)&hp16[((size_t)(b * 64 + tb + t)) * 128 + e4 * 4];
        *(float4*)&s_hp[t * 128 + e4 * 4] =
            make_float4(bf_lo(p.x), bf_hi(p.x), bf_lo(p.y), bf_hi(p.y));
    }
    if (tid < 128) s_hw[tid] = hwg[tid];
    if (tid < WIN) s_ci[tid] = citems[b * WIN + tid];
    if (wid == 0) {
        const int boolmode = flagp[0];
        const unsigned char* mb = (const unsigned char*)mask_raw;
        const int*           mi = (const int*)mask_raw;
        int base = 0;
#pragma unroll
        for (int r = 0; r < 4; ++r) {
            int w  = r * 64 + lane;
            int mv = 1;
            if (w < WIN) mv = boolmode ? (int)mb[b * WIN + w] : mi[b * WIN + w];
            unsigned long long act = __ballot(mv == 0);
            if (mv == 0)
                s_widx[base + __popcll(act & ((1ull << lane) - 1ull))] = w;
            base += __popcll(act);
        }
        if (lane == 0) s_m = base;
    }
    __syncthreads();

    const int m = s_m;
    const float invn = 1.f / sqrtf(800.f + (float)m);   // 1000 - (200 - m)
    size_t orow = ((size_t)(b * 64 + tb + t0)) * 128;

    if (m == 0) {
        *(float2*)&outp[orow + lane * 2]       = make_float2(0.f, 0.f);
        *(float2*)&outp[orow + 128 + lane * 2] = make_float2(0.f, 0.f);
        return;
    }

    const uint2*  hq2g = (const uint2*)hqT16;         // slot = (b*32+nc)*WPAD + w
    const float4* hw4p = (const float4*)s_hw;
    const float4* hp4a = (const float4*)&s_hp[t0 * 128];
    const float4* hp4b = hp4a + 32;
    const float4* cv4  = (const float4*)cvecs;
    const int mc = m - 1;

#define SC(J, K, HV, P)                                                        \
    va[J][K] += hwv.x * fmaxf(HV.x + P.x, 0.f) + hwv.y * fmaxf(HV.y + P.y, 0.f)\
              + hwv.z * fmaxf(HV.z + P.z, 0.f) + hwv.w * fmaxf(HV.w + P.w, 0.f);

    if (m <= 128) {
        // ---- stage: hq (bf16 gather -> fp32), k (fp32 direct) ----
        for (int i = tid; i < 4096; i += 1024) {
            int nc = i >> 7, w2 = i & 127;
            if (w2 < m) {
                uint2 p = hq2g[(size_t)(b * 32 + nc) * WPAD + s_widx[w2]];
                s_hq4[nc * 128 + w2] =
                    make_float4(bf_lo(p.x), bf_hi(p.x), bf_lo(p.y), bf_hi(p.y));
            }
        }
        {
            const int e4 = tid & 31, w0 = tid >> 5;   // 32 row-groups
            for (int w2k = w0; w2k < m; w2k += 32)
                s_k4[w2k * 32 + e4] = cv4[(size_t)s_ci[s_widx[w2k]] * 32 + e4];
        }
        __syncthreads();

        // ---- score (fp32, R12-verified) ----
        float va[2][2];
        va[0][0] = va[0][1] = va[1][0] = va[1][1] = 0.f;
#pragma unroll 4
        for (int nc = 0; nc < 32; ++nc) {
            float4 hv0 = s_hq4[nc * 128 + lane];
            float4 hv1 = s_hq4[nc * 128 + 64 + lane];
            float4 hwv = hw4p[nc];
            float4 p0  = hp4a[nc];
            float4 p1  = hp4b[nc];
            SC(0, 0, hv0, p0) SC(0, 1, hv1, p0)
            SC(1, 0, hv0, p1) SC(1, 1, hv1, p1)
        }

        // ---- softmax (2 t, 2 tiles) ----
#pragma unroll
        for (int j = 0; j < 2; ++j) {
            float mx = -1e30f;
#pragma unroll
            for (int kt = 0; kt < 2; ++kt) {
                float v = (kt * 64 + lane < m) ? va[j][kt] : -1e30f;
                va[j][kt] = v;
                mx = fmaxf(mx, v);
            }
#pragma unroll
            for (int off = 32; off; off >>= 1) mx = fmaxf(mx, __shfl_xor(mx, off));
            float sum = 0.f;
#pragma unroll
            for (int kt = 0; kt < 2; ++kt) {
                float e = (va[j][kt] <= -1e29f) ? 0.f : __expf(va[j][kt] - mx);
                va[j][kt] = e;
                sum += e;
            }
#pragma unroll
            for (int off = 32; off; off >>= 1) sum += __shfl_xor(sum, off);
            float is = 1.f / sum;
            va[j][0] *= is; va[j][1] *= is;
        }

        // ---- PV from LDS fp32 k (exact) ----
        float2 po0 = make_float2(0.f, 0.f), po1 = make_float2(0.f, 0.f);
        const float2* s_k2 = (const float2*)s_k4;
#pragma unroll
        for (int kt = 0; kt < 2; ++kt) {
            if (kt * 64 < m) {
                const int wn = min(64, m - kt * 64);
#pragma unroll 4
                for (int w = 0; w < wn; ++w) {
                    float2 kv = s_k2[(kt * 64 + w) * 64 + lane];
                    float a0 = rdlane(va[0][kt], w);
                    float a1 = rdlane(va[1][kt], w);
                    po0.x += a0 * kv.x; po0.y += a0 * kv.y;
                    po1.x += a1 * kv.x; po1.y += a1 * kv.y;
                }
            }
        }
        *(float2*)&outp[orow + lane * 2]       = make_float2(po0.x * invn, po0.y * invn);
        *(float2*)&outp[orow + 128 + lane * 2] = make_float2(po1.x * invn, po1.y * invn);
    } else {
        // ---- m > 128 fallback (rare): direct-from-global ----
        int wreg[4];
#pragma unroll
        for (int kt = 0; kt < 4; ++kt) wreg[kt] = s_widx[min(kt * 64 + lane, mc)];
        float va[2][4];
#pragma unroll
        for (int j = 0; j < 2; ++j)
#pragma unroll
            for (int k = 0; k < 4; ++k) va[j][k] = 0.f;

#pragma unroll 2
        for (int nc = 0; nc < 32; ++nc) {
            const uint2* base = hq2g + (size_t)(b * 32 + nc) * WPAD;
            float4 hv[4];
#pragma unroll
            for (int kt = 0; kt < 4; ++kt) {
                uint2 hu = base[wreg[kt]];
                hv[kt] = make_float4(bf_lo(hu.x), bf_hi(hu.x), bf_lo(hu.y), bf_hi(hu.y));
            }
            float4 hwv = hw4p[nc];
            float4 p0 = hp4a[nc];
            float4 p1 = hp4b[nc];
            SC(0, 0, hv[0], p0) SC(0, 1, hv[1], p0) SC(0, 2, hv[2], p0) SC(0, 3, hv[3], p0)
            SC(1, 0, hv[0], p1) SC(1, 1, hv[1], p1) SC(1, 2, hv[2], p1) SC(1, 3, hv[3], p1)
        }

#pragma unroll
        for (int j = 0; j < 2; ++j) {
            float mx = -1e30f;
#pragma unroll
            for (int kt = 0; kt < 4; ++kt) {
                float v = (kt * 64 + lane < m) ? va[j][kt] : -1e30f;
                va[j][kt] = v;
                mx = fmaxf(mx, v);
            }
#pragma unroll
            for (int off = 32; off; off >>= 1) mx = fmaxf(mx, __shfl_xor(mx, off));
            float sum = 0.f;
#pragma unroll
            for (int kt = 0; kt < 4; ++kt) {
                float e = (va[j][kt] <= -1e29f) ? 0.f : __expf(va[j][kt] - mx);
                va[j][kt] = e;
                sum += e;
            }
#pragma unroll
            for (int off = 32; off; off >>= 1) sum += __shfl_xor(sum, off);
            float is = 1.f / sum;
#pragma unroll
            for (int kt = 0; kt < 4; ++kt) va[j][kt] *= is;
        }

        float2 po0 = make_float2(0.f, 0.f), po1 = make_float2(0.f, 0.f);
        const char* cvb = (const char*)cvecs;
#pragma unroll
        for (int kt = 0; kt < 4; ++kt) {
            if (kt * 64 < m) {
                const int wn = min(64, m - kt * 64);
                for (int w = 0; w < wn; ++w) {
                    unsigned off = (unsigned)s_ci[s_widx[kt * 64 + w]] * 512u;
                    float2 kv = *(const float2*)(cvb + off + lane * 8);
                    float a0 = rdlane(va[0][kt], w);
                    float a1 = rdlane(va[1][kt], w);
                    po0.x += a0 * kv.x; po0.y += a0 * kv.y;
                    po1.x += a1 * kv.x; po1.y += a1 * kv.y;
                }
            }
        }
        *(float2*)&outp[orow + lane * 2]       = make_float2(po0.x * invn, po0.y * invn);
        *(float2*)&outp[orow + 128 + lane * 2] = make_float2(po1.x * invn, po1.y * invn);
    }
#undef SC
}

// ---------------------------------------------------------------------------
extern "C" void kernel_launch(void* const* d_in, const int* in_sizes, int n_in,
                              void* d_out, int out_size, void* d_ws, size_t ws_size,
                              hipStream_t stream) {
    const float* tvecs = (const float*)d_in[0];
    const float* cvecs = (const float*)d_in[1];
    const float* Ww    = (const float*)d_in[2];
    const float* Wb    = (const float*)d_in[3];
    const float* hw    = (const float*)d_in[4];
    // d_in[5] = h_b : unused (softmax shift-invariance)
    const int* titems  = (const int*)d_in[6];
    const int* citems  = (const int*)d_in[7];
    const void* mask   = d_in[8];
    float* out         = (float*)d_out;

    const size_t hp_elems = (size_t)BB * NT * 128;              // ushorts
    const size_t hq_elems = (size_t)BB * 32 * WPAD * 4;         // ushorts
    const size_t needed = 256 + hp_elems * 2 + hq_elems * 2;
    if (ws_size < needed) return;

    int*    flag  = (int*)d_ws;
    ushort* hp16  = (ushort*)((char*)d_ws + 256);
    ushort* hqT16 = hp16 + hp_elems;

    proj_kernel<<<265, 512, 0, stream>>>(tvecs, cvecs, titems, citems,
                                         Ww, Wb, (const int*)mask, flag,
                                         hp16, hqT16);
    attn_kernel<<<BB * 2, 1024, 0, stream>>>(cvecs, citems, mask, flag,
                                             hw, hp16, hqT16, out);
}